// Round 2
// 1895.053 us; speedup vs baseline: 2.9671x; 2.9671x over previous
//
#include <hip/hip_runtime.h>

#define BATCH 2
#define SEQ   2048
#define HIDSZ 4096
#define NH    32
#define NKV   8
#define HD    128
#define HALFD 64
#define MROWS (BATCH*SEQ)   // 4096
#define KVDIM (NKV*HD)      // 1024

typedef _Float16 f16;
typedef __attribute__((ext_vector_type(4))) float    fx4;
typedef __attribute__((ext_vector_type(4))) _Float16 half4;
typedef __attribute__((ext_vector_type(8))) _Float16 half8;

__device__ __forceinline__ float ldf(const f16* p)   { return (float)*p; }
__device__ __forceinline__ float ldf(const float* p) { return *p; }
__device__ __forceinline__ void  stf(f16* p, float v)   { *p = (f16)v; }
__device__ __forceinline__ void  stf(float* p, float v) { *p = v; }

// ---------------- MFMA GEMM: C[M,N] = A[M,K] @ B[K,N], row-major ------------
// 128x128 tile, BK=32, 256 threads = 4 waves (2x2 of 64x64), f16 MFMA
// 16x16x32, fp32 accum. A/B converted fp32->f16 during reg-staged LDS write.
// B micro-transposed 4x4 in regs to k-major LDS; XOR swizzle k^=8*((n>>2)&3)
// makes frag ds_read_b128 bank-conflict-free.
template<typename T> struct avec;
template<> struct avec<float> { using type = fx4; };
template<> struct avec<f16>   { using type = half4; };

__device__ __forceinline__ half4 toh4(fx4 v) {
    half4 h; h[0] = (f16)v[0]; h[1] = (f16)v[1]; h[2] = (f16)v[2]; h[3] = (f16)v[3];
    return h;
}
__device__ __forceinline__ half4 toh4(half4 v) { return v; }

template<typename TA, typename TC>
__global__ __launch_bounds__(256)
void gemm_mfma(const TA* __restrict__ A, const float* __restrict__ B,
               TC* __restrict__ C, int M, int N, int K) {
    __shared__ f16 As[128][32];   // [m][k]
    __shared__ f16 Bs[128][32];   // [n][k ^ swz(n)]
    const int tid  = threadIdx.x;
    const int wave = tid >> 6, lane = tid & 63;
    const int c    = lane & 15, qd = lane >> 4;
    const int wr   = (wave >> 1) * 64, wc = (wave & 1) * 64;
    const int bx = blockIdx.x, by = blockIdx.y;

    // staging maps: A thread = 4 rows (am+32u) x 4 k (ak..ak+3)
    //               B thread = 4 k rows (bk+u)  x 4 n (bn..bn+3)
    const int am = tid >> 3;
    const int ak = (tid & 7) * 4;
    const int bn = (tid & 31) * 4;
    const int bk = (tid >> 5) * 4;

    const TA*    Ap = A + (size_t)(by * 128 + am) * K + ak;
    const float* Bp = B + (size_t)bk * N + bx * 128 + bn;

    fx4 acc[4][4];
#pragma unroll
    for (int i = 0; i < 4; i++)
#pragma unroll
        for (int j = 0; j < 4; j++)
#pragma unroll
            for (int r = 0; r < 4; r++) acc[i][j][r] = 0.f;

    using AT = typename avec<TA>::type;
    AT  areg[4];
    fx4 breg[4];
#pragma unroll
    for (int u = 0; u < 4; u++) {
        areg[u] = *(const AT*)(Ap + (size_t)u * 32 * K);
        breg[u] = *(const fx4*)(Bp + (size_t)u * N);
    }

    for (int k0 = 0; k0 < K; k0 += 32) {
        // ---- regs -> LDS (with f16 convert; B transposed 4x4) ----
#pragma unroll
        for (int u = 0; u < 4; u++)
            *(half4*)&As[am + u * 32][ak] = toh4(areg[u]);
#pragma unroll
        for (int v = 0; v < 4; v++) {
            const int n  = bn + v;
            const int kx = bk ^ (8 * ((n >> 2) & 3));
            half4 h;
#pragma unroll
            for (int u = 0; u < 4; u++) h[u] = (f16)breg[u][v];
            *(half4*)&Bs[n][kx] = h;
        }
        __syncthreads();
        // ---- prefetch next K-tile (overlaps with MFMA below) ----
        if (k0 + 32 < K) {
#pragma unroll
            for (int u = 0; u < 4; u++) {
                areg[u] = *(const AT*)(Ap + (size_t)u * 32 * K + (k0 + 32));
                breg[u] = *(const fx4*)(Bp + (size_t)(k0 + 32 + u) * N);
            }
        }
        // ---- fragments + 16 MFMAs ----
        half8 af[4], bf[4];
#pragma unroll
        for (int i = 0; i < 4; i++)
            af[i] = *(const half8*)&As[wr + i * 16 + c][qd * 8];
#pragma unroll
        for (int j = 0; j < 4; j++) {
            const int n = wc + j * 16 + c;
            bf[j] = *(const half8*)&Bs[n][(qd * 8) ^ (8 * ((n >> 2) & 3))];
        }
#pragma unroll
        for (int i = 0; i < 4; i++)
#pragma unroll
            for (int j = 0; j < 4; j++)
                acc[i][j] = __builtin_amdgcn_mfma_f32_16x16x32_f16(
                                af[i], bf[j], acc[i][j], 0, 0, 0);
        __syncthreads();
    }

    // C/D layout: row = qd*4+r, col = c  (dtype-independent, m89/m101)
#pragma unroll
    for (int i = 0; i < 4; i++)
#pragma unroll
        for (int j = 0; j < 4; j++)
#pragma unroll
            for (int r = 0; r < 4; r++)
                stf(&C[(size_t)(by * 128 + wr + i * 16 + qd * 4 + r) * N
                       + bx * 128 + wc + j * 16 + c], acc[i][j][r]);
}

// ---------------- RoPE (in place, tensor of shape [MROWS, heads*HD]) --------
template<typename T>
__global__ void rope_kernel(T* __restrict__ t, int heads) {
    int idx = blockIdx.x * blockDim.x + threadIdx.x;
    int i   = idx & (HALFD - 1);
    int r   = idx >> 6;
    int h   = r % heads;
    int row = r / heads;
    int pos = row & (SEQ - 1);
    float inv_freq = expf(-(float)i * (9.210340371976184f / 64.0f));
    float ang = (float)pos * inv_freq;
    float s, c;
    sincosf(ang, &s, &c);
    size_t base = (size_t)row * ((size_t)heads * HD) + (size_t)h * HD;
    float x1 = ldf(&t[base + i]);
    float x2 = ldf(&t[base + i + HALFD]);
    stf(&t[base + i],         x1 * c - x2 * s);
    stf(&t[base + i + HALFD], x2 * c + x1 * s);
}

// ---------------- V transpose: v[B*SEQ][KVDIM] -> vt[B][NKV][HD][SEQ] -------
__global__ __launch_bounds__(256)
void transpose_v_kernel(const f16* __restrict__ v, f16* __restrict__ vt) {
    __shared__ short tile[32][33];
    int ts = blockIdx.x * 32;          // seq tile
    int td = blockIdx.y * 32;          // d tile within head
    int bk = blockIdx.z;               // b*NKV + kvh
    int b = bk >> 3, kvh = bk & 7;
    int tx = threadIdx.x & 31, ty = threadIdx.x >> 5;
    const short* vp = (const short*)v;
    short* vtp = (short*)vt;
#pragma unroll
    for (int i = 0; i < 4; i++) {
        int s = ts + ty + i * 8;
        tile[ty + i * 8][tx] = vp[(size_t)(b * SEQ + s) * KVDIM + kvh * HD + td + tx];
    }
    __syncthreads();
#pragma unroll
    for (int i = 0; i < 4; i++) {
        int d = td + ty + i * 8;
        vtp[((size_t)(b * NKV + kvh) * HD + d) * SEQ + ts + tx] = tile[tx][ty + i * 8];
    }
}

// ---------------- Flash attention: block = (b, h, 64-row q tile) ------------
// 4 waves; wave w owns q rows [q0+16w, q0+16w+15]. mfma_f32_16x16x32_f16.
// A-frag: A[m=lane&15][k=quad*8+j]; B-frag: B[k=quad*8+j][n=lane&15];
// C/D: row=quad*4+reg, col=lane&15.  (m89/m91/m120-verified layouts)
__global__ __launch_bounds__(256)
void flash_attn_kernel(const f16* __restrict__ q, const f16* __restrict__ k,
                       const f16* __restrict__ vt, f16* __restrict__ ao) {
    int qt = blockIdx.x, h = blockIdx.y, b = blockIdx.z;
    int kvh = h >> 2;
    int tid = threadIdx.x;
    int wave = tid >> 6, lane = tid & 63;
    int col = lane & 15, quad = lane >> 4;
    int q0 = qt * 64;

    __shared__ f16 lds_p[4][16][64];   // per-wave P staging (C->A layout)

    // Q frags: qf[ks] = Q[q0+16w+col][h*HD + ks*32 + quad*8 .. +7]
    half8 qf[4];
    {
        const f16* qbase = q +
            (size_t)(b * SEQ + q0 + wave * 16 + col) * HIDSZ + h * HD + quad * 8;
#pragma unroll
        for (int ks = 0; ks < 4; ks++)
            qf[ks] = *(const half8*)(qbase + ks * 32);
    }

    float m_i[4], l_i[4];
#pragma unroll
    for (int r = 0; r < 4; r++) { m_i[r] = -1e30f; l_i[r] = 0.f; }
    fx4 O[8];
#pragma unroll
    for (int n = 0; n < 8; n++)
#pragma unroll
        for (int r = 0; r < 4; r++) O[n][r] = 0.f;

    const f16* kbase  = k + (size_t)(b * SEQ) * KVDIM + kvh * HD + quad * 8;
    const f16* vtbase = vt + ((size_t)(b * NKV + kvh) * HD + col) * SEQ + quad * 8;
    const float scale = 0.08838834764831845f;   // 1/sqrt(128)

    for (int j0 = 0; j0 <= q0; j0 += 64) {
        // ---- S[16 x 64] = Q Kt (4 n-tiles of 16) ----
        fx4 S[4];
#pragma unroll
        for (int nt = 0; nt < 4; nt++) {
            fx4 acc;
#pragma unroll
            for (int r = 0; r < 4; r++) acc[r] = 0.f;
            const f16* kp = kbase + (size_t)(j0 + nt * 16 + col) * KVDIM;
#pragma unroll
            for (int ks = 0; ks < 4; ks++)
                acc = __builtin_amdgcn_mfma_f32_16x16x32_f16(
                          qf[ks], *(const half8*)(kp + ks * 32), acc, 0, 0, 0);
#pragma unroll
            for (int r = 0; r < 4; r++) S[nt][r] = acc[r] * scale;
        }
        // ---- causal mask (diagonal tile only) ----
        if (j0 == q0) {
            int rowb = wave * 16 + quad * 4;
#pragma unroll
            for (int nt = 0; nt < 4; nt++)
#pragma unroll
                for (int r = 0; r < 4; r++)
                    if (nt * 16 + col > rowb + r) S[nt][r] = -1e30f;
        }
        // ---- online softmax over this tile ----
        float mn[4], alpha[4];
#pragma unroll
        for (int r = 0; r < 4; r++) {
            float mx = fmaxf(fmaxf(S[0][r], S[1][r]), fmaxf(S[2][r], S[3][r]));
#pragma unroll
            for (int d = 8; d >= 1; d >>= 1) mx = fmaxf(mx, __shfl_xor(mx, d, 64));
            mn[r] = fmaxf(m_i[r], mx);
            alpha[r] = __expf(m_i[r] - mn[r]);
            m_i[r] = mn[r];
        }
#pragma unroll
        for (int nt = 0; nt < 4; nt++)
#pragma unroll
            for (int r = 0; r < 4; r++) S[nt][r] = __expf(S[nt][r] - mn[r]);
#pragma unroll
        for (int r = 0; r < 4; r++) {
            float s = (S[0][r] + S[1][r]) + (S[2][r] + S[3][r]);
#pragma unroll
            for (int d = 8; d >= 1; d >>= 1) s += __shfl_xor(s, d, 64);
            l_i[r] = l_i[r] * alpha[r] + s;
        }
#pragma unroll
        for (int n = 0; n < 8; n++)
#pragma unroll
            for (int r = 0; r < 4; r++) O[n][r] *= alpha[r];
        // ---- P: C-layout regs -> LDS -> A-layout frags ----
#pragma unroll
        for (int nt = 0; nt < 4; nt++)
#pragma unroll
            for (int r = 0; r < 4; r++)
                lds_p[wave][quad * 4 + r][nt * 16 + col] = (f16)S[nt][r];
        __syncthreads();
        half8 pf[2];
#pragma unroll
        for (int ks2 = 0; ks2 < 2; ks2++)
            pf[ks2] = *(const half8*)&lds_p[wave][col][ks2 * 32 + quad * 8];
        // ---- O += P V (8 d-tiles of 16) ----
#pragma unroll
        for (int n = 0; n < 8; n++) {
            const f16* vp = vtbase + (size_t)(n * 16) * SEQ + j0;
#pragma unroll
            for (int ks2 = 0; ks2 < 2; ks2++)
                O[n] = __builtin_amdgcn_mfma_f32_16x16x32_f16(
                           pf[ks2], *(const half8*)(vp + ks2 * 32), O[n], 0, 0, 0);
        }
        __syncthreads();
    }

    // ---- epilogue: normalize, store (C layout) ----
#pragma unroll
    for (int r = 0; r < 4; r++) l_i[r] = 1.f / l_i[r];
    int orow = q0 + wave * 16 + quad * 4;
#pragma unroll
    for (int n = 0; n < 8; n++)
#pragma unroll
        for (int r = 0; r < 4; r++)
            ao[(size_t)(b * SEQ + orow + r) * HIDSZ + h * HD + n * 16 + col] =
                (f16)(O[n][r] * l_i[r]);
}

// ---------------------------------------------------------------------------
extern "C" void kernel_launch(void* const* d_in, const int* in_sizes, int n_in,
                              void* d_out, int out_size, void* d_ws, size_t ws_size,
                              hipStream_t stream) {
    const float* x  = (const float*)d_in[0];
    const float* wq = (const float*)d_in[1];
    const float* wk = (const float*)d_in[2];
    const float* wv = (const float*)d_in[3];
    const float* wo = (const float*)d_in[4];
    float* out = (float*)d_out;

    // ws: q 32MB | k 8MB | v 8MB | ao 32MB | vt 8MB  = 88MB f16
    f16* q  = (f16*)d_ws;                              // [4096][4096]
    f16* k  = q + (size_t)MROWS * HIDSZ;               // [4096][1024]
    f16* v  = k + (size_t)MROWS * KVDIM;               // [4096][1024]
    f16* ao = v + (size_t)MROWS * KVDIM;               // [4096][4096]
    f16* vt = ao + (size_t)MROWS * HIDSZ;              // [2][8][128][2048]

    gemm_mfma<float, f16><<<dim3(HIDSZ / 128, MROWS / 128), 256, 0, stream>>>(
        x, wq, q, MROWS, HIDSZ, HIDSZ);
    gemm_mfma<float, f16><<<dim3(KVDIM / 128, MROWS / 128), 256, 0, stream>>>(
        x, wk, k, MROWS, KVDIM, HIDSZ);
    gemm_mfma<float, f16><<<dim3(KVDIM / 128, MROWS / 128), 256, 0, stream>>>(
        x, wv, v, MROWS, KVDIM, HIDSZ);

    rope_kernel<f16><<<(MROWS * NH * HALFD) / 256, 256, 0, stream>>>(q, NH);
    rope_kernel<f16><<<(MROWS * NKV * HALFD) / 256, 256, 0, stream>>>(k, NKV);

    transpose_v_kernel<<<dim3(SEQ / 32, HD / 32, BATCH * NKV), 256, 0, stream>>>(v, vt);

    flash_attn_kernel<<<dim3(SEQ / 64, NH, BATCH), 256, 0, stream>>>(q, k, vt, ao);

    gemm_mfma<f16, float><<<dim3(HIDSZ / 128, MROWS / 128), 256, 0, stream>>>(
        ao, wo, out, MROWS, HIDSZ, HIDSZ);
}

// Round 4
// 1158.941 us; speedup vs baseline: 4.8517x; 1.6352x over previous
//
#include <hip/hip_runtime.h>

#define BATCH 2
#define SEQ   2048
#define HIDSZ 4096
#define NH    32
#define NKV   8
#define HD    128
#define HALFD 64
#define MROWS (BATCH*SEQ)   // 4096
#define KVDIM (NKV*HD)      // 1024

typedef _Float16 f16;
typedef __attribute__((ext_vector_type(4))) float    fx4;
typedef __attribute__((ext_vector_type(4))) _Float16 half4;
typedef __attribute__((ext_vector_type(8))) _Float16 half8;

__device__ __forceinline__ float ldf(const f16* p)   { return (float)*p; }
__device__ __forceinline__ float ldf(const float* p) { return *p; }
__device__ __forceinline__ void  stf(f16* p, float v)   { *p = (f16)v; }
__device__ __forceinline__ void  stf(float* p, float v) { *p = v; }

// ---------------- MFMA GEMM: C[M,N] = A[M,K] @ B[K,N], row-major ------------
// 128x128 tile, BK=32, 256 threads = 4 waves (2x2 of 64x64), f16 MFMA
// 16x16x32, fp32 accum. A/B converted fp32->f16 during reg-staged LDS write.
template<typename T> struct avec;
template<> struct avec<float> { using type = fx4; };
template<> struct avec<f16>   { using type = half4; };

__device__ __forceinline__ half4 toh4(fx4 v) {
    half4 h; h[0] = (f16)v[0]; h[1] = (f16)v[1]; h[2] = (f16)v[2]; h[3] = (f16)v[3];
    return h;
}
__device__ __forceinline__ half4 toh4(half4 v) { return v; }

template<typename TA, typename TC>
__global__ __launch_bounds__(256)
void gemm_mfma(const TA* __restrict__ A, const float* __restrict__ B,
               TC* __restrict__ C, int M, int N, int K) {
    __shared__ f16 As[128][32];   // [m][k]
    __shared__ f16 Bs[128][32];   // [n][k ^ swz(n)]
    const int tid  = threadIdx.x;
    const int wave = tid >> 6, lane = tid & 63;
    const int c    = lane & 15, qd = lane >> 4;
    const int wr   = (wave >> 1) * 64, wc = (wave & 1) * 64;
    const int bx = blockIdx.x, by = blockIdx.y;

    const int am = tid >> 3;
    const int ak = (tid & 7) * 4;
    const int bn = (tid & 31) * 4;
    const int bk = (tid >> 5) * 4;

    const TA*    Ap = A + (size_t)(by * 128 + am) * K + ak;
    const float* Bp = B + (size_t)bk * N + bx * 128 + bn;

    fx4 acc[4][4];
#pragma unroll
    for (int i = 0; i < 4; i++)
#pragma unroll
        for (int j = 0; j < 4; j++)
#pragma unroll
            for (int r = 0; r < 4; r++) acc[i][j][r] = 0.f;

    using AT = typename avec<TA>::type;
    AT  areg[4];
    fx4 breg[4];
#pragma unroll
    for (int u = 0; u < 4; u++) {
        areg[u] = *(const AT*)(Ap + (size_t)u * 32 * K);
        breg[u] = *(const fx4*)(Bp + (size_t)u * N);
    }

    for (int k0 = 0; k0 < K; k0 += 32) {
#pragma unroll
        for (int u = 0; u < 4; u++)
            *(half4*)&As[am + u * 32][ak] = toh4(areg[u]);
#pragma unroll
        for (int v = 0; v < 4; v++) {
            const int n  = bn + v;
            const int kx = bk ^ (8 * ((n >> 2) & 3));
            half4 h;
#pragma unroll
            for (int u = 0; u < 4; u++) h[u] = (f16)breg[u][v];
            *(half4*)&Bs[n][kx] = h;
        }
        __syncthreads();
        if (k0 + 32 < K) {
#pragma unroll
            for (int u = 0; u < 4; u++) {
                areg[u] = *(const AT*)(Ap + (size_t)u * 32 * K + (k0 + 32));
                breg[u] = *(const fx4*)(Bp + (size_t)(k0 + 32 + u) * N);
            }
        }
        half8 af[4], bf[4];
#pragma unroll
        for (int i = 0; i < 4; i++)
            af[i] = *(const half8*)&As[wr + i * 16 + c][qd * 8];
#pragma unroll
        for (int j = 0; j < 4; j++) {
            const int n = wc + j * 16 + c;
            bf[j] = *(const half8*)&Bs[n][(qd * 8) ^ (8 * ((n >> 2) & 3))];
        }
#pragma unroll
        for (int i = 0; i < 4; i++)
#pragma unroll
            for (int j = 0; j < 4; j++)
                acc[i][j] = __builtin_amdgcn_mfma_f32_16x16x32_f16(
                                af[i], bf[j], acc[i][j], 0, 0, 0);
        __syncthreads();
    }

#pragma unroll
    for (int i = 0; i < 4; i++)
#pragma unroll
        for (int j = 0; j < 4; j++)
#pragma unroll
            for (int r = 0; r < 4; r++)
                stf(&C[(size_t)(by * 128 + wr + i * 16 + qd * 4 + r) * N
                       + bx * 128 + wc + j * 16 + c], acc[i][j][r]);
}

// ---------------- RoPE (in place, tensor of shape [MROWS, heads*HD]) --------
template<typename T>
__global__ void rope_kernel(T* __restrict__ t, int heads) {
    int idx = blockIdx.x * blockDim.x + threadIdx.x;
    int i   = idx & (HALFD - 1);
    int r   = idx >> 6;
    int h   = r % heads;
    int row = r / heads;
    int pos = row & (SEQ - 1);
    float inv_freq = expf(-(float)i * (9.210340371976184f / 64.0f));
    float ang = (float)pos * inv_freq;
    float s, c;
    sincosf(ang, &s, &c);
    size_t base = (size_t)row * ((size_t)heads * HD) + (size_t)h * HD;
    float x1 = ldf(&t[base + i]);
    float x2 = ldf(&t[base + i + HALFD]);
    stf(&t[base + i],         x1 * c - x2 * s);
    stf(&t[base + i + HALFD], x2 * c + x1 * s);
}

// ---------------- V transpose: v[B*SEQ][KVDIM] -> vt[B][NKV][HD][SEQ] -------
__global__ __launch_bounds__(256)
void transpose_v_kernel(const f16* __restrict__ v, f16* __restrict__ vt) {
    __shared__ short tile[32][33];
    int ts = blockIdx.x * 32;          // seq tile
    int td = blockIdx.y * 32;          // d tile within head
    int bk = blockIdx.z;               // b*NKV + kvh
    int b = bk >> 3, kvh = bk & 7;
    int tx = threadIdx.x & 31, ty = threadIdx.x >> 5;
    const short* vp = (const short*)v;
    short* vtp = (short*)vt;
#pragma unroll
    for (int i = 0; i < 4; i++) {
        int s = ts + ty + i * 8;
        tile[ty + i * 8][tx] = vp[(size_t)(b * SEQ + s) * KVDIM + kvh * HD + td + tx];
    }
    __syncthreads();
#pragma unroll
    for (int i = 0; i < 4; i++) {
        int d = td + ty + i * 8;
        vtp[((size_t)(b * NKV + kvh) * HD + d) * SEQ + ts + tx] = tile[tx][ty + i * 8];
    }
}

// ---------------- Flash attention --------------------------------------------
// Block = (b, h, q-tile PAIR {bx, 31-bx}) -> every block does exactly 33
// KV-iterations (load balance). 4 waves; wave w owns q rows [q0+16w .. +15].
// K[64][128] and V^T[128][64] staged cooperatively in LDS per KV tile,
// XOR-swizzled (elem ^= (row&7)<<3) for conflict-free ds_read_b128.
// Async-stage split: next tile's global loads issued at iter top (regs),
// ds_write after post-PV barrier. P round-trip is wave-local (no barrier).
__global__ __launch_bounds__(256)
void flash_attn_kernel(const f16* __restrict__ q, const f16* __restrict__ k,
                       const f16* __restrict__ vt, f16* __restrict__ ao) {
    const int NT = SEQ / 64;               // 32 q-tiles
    int h = blockIdx.y, b = blockIdx.z;
    int kvh = h >> 2;
    int tid = threadIdx.x;
    int wave = tid >> 6, lane = tid & 63;
    int col = lane & 15, quad = lane >> 4;

    __shared__ f16 Ks[64 * 128];   // [seqrow][d ^ swz]
    __shared__ f16 Vs[128 * 64];   // [d][seq ^ swz]
    __shared__ f16 Ps[4 * 16 * 64];// per-wave [qrow][kcol ^ swz]

    const f16* kg0 = k  + (size_t)(b * SEQ) * KVDIM + kvh * HD;
    const f16* vg0 = vt + ((size_t)(b * NKV + kvh) * HD) * SEQ;
    const float scale = 0.08838834764831845f;   // 1/sqrt(128)

#pragma unroll 1
    for (int hf = 0; hf < 2; ++hf) {
        const int qv  = hf ? (NT - 1 - (int)blockIdx.x) : (int)blockIdx.x;
        const int q0  = qv * 64;
        const int nkv = qv + 1;

        // Q frags: qf[ks] = Q[q0+16w+col][h*HD + ks*32 + quad*8 .. +7]
        half8 qf[4];
        {
            const f16* qbase = q +
                (size_t)(b * SEQ + q0 + wave * 16 + col) * HIDSZ + h * HD + quad * 8;
#pragma unroll
            for (int ks = 0; ks < 4; ks++)
                qf[ks] = *(const half8*)(qbase + ks * 32);
        }

        float m_i[4], l_i[4];
#pragma unroll
        for (int r = 0; r < 4; r++) { m_i[r] = -1e30f; l_i[r] = 0.f; }
        fx4 O[8];
#pragma unroll
        for (int n = 0; n < 8; n++)
#pragma unroll
            for (int r = 0; r < 4; r++) O[n][r] = 0.f;

        // K tile: 64 rows x 128 d  = 1024 half8 -> 4 iters x 256 thr
        // V tile: 128 rows x 64 s  = 1024 half8 -> 4 iters x 256 thr
        half8 kreg[4], vreg[4];
        // ---- prologue: stage KV tile j0=0 ----
#pragma unroll
        for (int i = 0; i < 4; i++) {
            int c2 = tid + i * 256, row = c2 >> 4, d0 = (c2 & 15) * 8;
            kreg[i] = *(const half8*)(kg0 + (size_t)row * KVDIM + d0);
        }
#pragma unroll
        for (int i = 0; i < 4; i++) {
            int c2 = tid + i * 256, row = c2 >> 3, s0 = (c2 & 7) * 8;
            vreg[i] = *(const half8*)(vg0 + (size_t)row * SEQ + s0);
        }
        __syncthreads();   // previous tile's readers done before overwrite
#pragma unroll
        for (int i = 0; i < 4; i++) {
            int c2 = tid + i * 256, row = c2 >> 4, d0 = (c2 & 15) * 8;
            *(half8*)&Ks[row * 128 + (d0 ^ ((row & 7) << 3))] = kreg[i];
        }
#pragma unroll
        for (int i = 0; i < 4; i++) {
            int c2 = tid + i * 256, row = c2 >> 3, s0 = (c2 & 7) * 8;
            *(half8*)&Vs[row * 64 + (s0 ^ ((row & 7) << 3))] = vreg[i];
        }
        __syncthreads();

#pragma unroll 1
        for (int t = 0; t < nkv; ++t) {
            const int j0  = t * 64;
            const bool pre = (t + 1 < nkv);
            // ---- issue next tile's global loads (latency hides under compute)
            if (pre) {
                const int jn = j0 + 64;
#pragma unroll
                for (int i = 0; i < 4; i++) {
                    int c2 = tid + i * 256, row = c2 >> 4, d0 = (c2 & 15) * 8;
                    kreg[i] = *(const half8*)(kg0 + (size_t)(jn + row) * KVDIM + d0);
                }
#pragma unroll
                for (int i = 0; i < 4; i++) {
                    int c2 = tid + i * 256, row = c2 >> 3, s0 = (c2 & 7) * 8;
                    vreg[i] = *(const half8*)(vg0 + (size_t)row * SEQ + jn + s0);
                }
            }
            // ---- S[16 x 64] = Q Kt from LDS ----
            fx4 S[4];
#pragma unroll
            for (int nt = 0; nt < 4; nt++) {
                fx4 acc;
#pragma unroll
                for (int r = 0; r < 4; r++) acc[r] = 0.f;
                const int row = nt * 16 + col;
#pragma unroll
                for (int ks = 0; ks < 4; ks++) {
                    half8 kf = *(const half8*)&Ks[row * 128 +
                                   ((ks * 32 + quad * 8) ^ ((row & 7) << 3))];
                    acc = __builtin_amdgcn_mfma_f32_16x16x32_f16(qf[ks], kf, acc, 0, 0, 0);
                }
#pragma unroll
                for (int r = 0; r < 4; r++) S[nt][r] = acc[r] * scale;
            }
            // ---- causal mask (diagonal tile only) ----
            if (j0 == q0) {
                int rowb = wave * 16 + quad * 4;
#pragma unroll
                for (int nt = 0; nt < 4; nt++)
#pragma unroll
                    for (int r = 0; r < 4; r++)
                        if (nt * 16 + col > rowb + r) S[nt][r] = -1e30f;
            }
            // ---- online softmax ----
            float mn[4], alpha[4];
#pragma unroll
            for (int r = 0; r < 4; r++) {
                float mx = fmaxf(fmaxf(S[0][r], S[1][r]), fmaxf(S[2][r], S[3][r]));
#pragma unroll
                for (int d = 8; d >= 1; d >>= 1) mx = fmaxf(mx, __shfl_xor(mx, d, 64));
                mn[r] = fmaxf(m_i[r], mx);
                alpha[r] = __expf(m_i[r] - mn[r]);
                m_i[r] = mn[r];
            }
#pragma unroll
            for (int nt = 0; nt < 4; nt++)
#pragma unroll
                for (int r = 0; r < 4; r++) S[nt][r] = __expf(S[nt][r] - mn[r]);
#pragma unroll
            for (int r = 0; r < 4; r++) {
                float s = (S[0][r] + S[1][r]) + (S[2][r] + S[3][r]);
#pragma unroll
                for (int d = 8; d >= 1; d >>= 1) s += __shfl_xor(s, d, 64);
                l_i[r] = l_i[r] * alpha[r] + s;
            }
#pragma unroll
            for (int n = 0; n < 8; n++)
#pragma unroll
                for (int r = 0; r < 4; r++) O[n][r] *= alpha[r];
            // ---- P: C-layout regs -> LDS -> A-layout frags (wave-local) ----
#pragma unroll
            for (int nt = 0; nt < 4; nt++)
#pragma unroll
                for (int r = 0; r < 4; r++) {
                    int prow = quad * 4 + r;
                    Ps[wave * 1024 + prow * 64 +
                       ((nt * 16 + col) ^ ((prow & 7) << 3))] = (f16)S[nt][r];
                }
            half8 pf[2];
#pragma unroll
            for (int ks2 = 0; ks2 < 2; ks2++)
                pf[ks2] = *(const half8*)&Ps[wave * 1024 + col * 64 +
                              ((ks2 * 32 + quad * 8) ^ ((col & 7) << 3))];
            // ---- O += P V from LDS (8 d-tiles of 16) ----
#pragma unroll
            for (int n = 0; n < 8; n++) {
                const int row = n * 16 + col;
#pragma unroll
                for (int ks2 = 0; ks2 < 2; ks2++) {
                    half8 vf = *(const half8*)&Vs[row * 64 +
                                   ((ks2 * 32 + quad * 8) ^ ((row & 7) << 3))];
                    O[n] = __builtin_amdgcn_mfma_f32_16x16x32_f16(pf[ks2], vf, O[n], 0, 0, 0);
                }
            }
            // ---- write-late: commit prefetched tile to LDS ----
            if (pre) {
                __syncthreads();   // all waves done reading Ks/Vs
#pragma unroll
                for (int i = 0; i < 4; i++) {
                    int c2 = tid + i * 256, row = c2 >> 4, d0 = (c2 & 15) * 8;
                    *(half8*)&Ks[row * 128 + (d0 ^ ((row & 7) << 3))] = kreg[i];
                }
#pragma unroll
                for (int i = 0; i < 4; i++) {
                    int c2 = tid + i * 256, row = c2 >> 3, s0 = (c2 & 7) * 8;
                    *(half8*)&Vs[row * 64 + (s0 ^ ((row & 7) << 3))] = vreg[i];
                }
                __syncthreads();
            }
        }

        // ---- epilogue: normalize, store (C layout) ----
#pragma unroll
        for (int r = 0; r < 4; r++) l_i[r] = 1.f / l_i[r];
        int orow = q0 + wave * 16 + quad * 4;
#pragma unroll
        for (int n = 0; n < 8; n++)
#pragma unroll
            for (int r = 0; r < 4; r++)
                ao[(size_t)(b * SEQ + orow + r) * HIDSZ + h * HD + n * 16 + col] =
                    (f16)(O[n][r] * l_i[r]);
    }
}

// ---------------------------------------------------------------------------
extern "C" void kernel_launch(void* const* d_in, const int* in_sizes, int n_in,
                              void* d_out, int out_size, void* d_ws, size_t ws_size,
                              hipStream_t stream) {
    const float* x  = (const float*)d_in[0];
    const float* wq = (const float*)d_in[1];
    const float* wk = (const float*)d_in[2];
    const float* wv = (const float*)d_in[3];
    const float* wo = (const float*)d_in[4];
    float* out = (float*)d_out;

    // ws: q 32MB | k 8MB | v 8MB | ao 32MB | vt 8MB  = 88MB f16
    f16* q  = (f16*)d_ws;                              // [4096][4096]
    f16* k  = q + (size_t)MROWS * HIDSZ;               // [4096][1024]
    f16* v  = k + (size_t)MROWS * KVDIM;               // [4096][1024]
    f16* ao = v + (size_t)MROWS * KVDIM;               // [4096][4096]
    f16* vt = ao + (size_t)MROWS * HIDSZ;              // [2][8][128][2048]

    gemm_mfma<float, f16><<<dim3(HIDSZ / 128, MROWS / 128), 256, 0, stream>>>(
        x, wq, q, MROWS, HIDSZ, HIDSZ);
    gemm_mfma<float, f16><<<dim3(KVDIM / 128, MROWS / 128), 256, 0, stream>>>(
        x, wk, k, MROWS, KVDIM, HIDSZ);
    gemm_mfma<float, f16><<<dim3(KVDIM / 128, MROWS / 128), 256, 0, stream>>>(
        x, wv, v, MROWS, KVDIM, HIDSZ);

    rope_kernel<f16><<<(MROWS * NH * HALFD) / 256, 256, 0, stream>>>(q, NH);
    rope_kernel<f16><<<(MROWS * NKV * HALFD) / 256, 256, 0, stream>>>(k, NKV);

    transpose_v_kernel<<<dim3(SEQ / 32, HD / 32, BATCH * NKV), 256, 0, stream>>>(v, vt);

    flash_attn_kernel<<<dim3(SEQ / 128, NH, BATCH), 256, 0, stream>>>(q, k, vt, ao);

    gemm_mfma<f16, float><<<dim3(HIDSZ / 128, MROWS / 128), 256, 0, stream>>>(
        ao, wo, out, MROWS, HIDSZ, HIDSZ);
}